// Round 4
// baseline (3076.778 us; speedup 1.0000x reference)
//
#include <hip/hip_runtime.h>
#include <cfloat>
#include <math.h>

#define NOBS   256
#define NY     50
#define NX     30
#define NITER  400
#define LRATE  0.05f
#define CSTR   260     // ep_t column stride (floats)
#define THRANK 40      // persisted threshold tracks the rank-40 element (aN <= 25.6 always)
#define SPB    2       // scenarios per block: 2 waves/SIMD -> mutual latency hiding

__device__ __forceinline__ float rl_f(float x, int k) {
  // v_readlane: SGPR broadcast, no DS-pipe traffic
  return __int_as_float(__builtin_amdgcn_readlane(__float_as_int(x), k));
}

// wave64 max-reduce via DPP: row_shr 1,2,4,8 then row_bcast:15, row_bcast:31 -> lane 63 has max.
#define DPP_MAXSTEP(x, ctrl)                                                       \
  x = fmaxf(x, __int_as_float(__builtin_amdgcn_update_dpp(                         \
        __float_as_int(x), __float_as_int(x), (ctrl), 0xF, 0xF, false)))

__global__ __launch_bounds__(512) void dro_kernel(
    const float* __restrict__ X, const float* __restrict__ Y,
    const float* __restrict__ W, const float* __restrict__ B,
    const float* __restrict__ DLT, const float* __restrict__ GMM,
    float* __restrict__ out)
{
  __shared__ __align__(16) float ep_t[51 * CSTR];              // 53040 B, shared by both scenarios
  __shared__ __align__(16) unsigned long long rrk[SPB][NOBS];  // full key list (fallback scan)
  __shared__ __align__(16) unsigned long long ckey[SPB][320];  // compacted candidates + sentinel pads
  __shared__ __align__(16) float red[SPB][NOBS];               // per-wave column partials
  __shared__ float wmax4[SPB][4];
  __shared__ int   wcnt[SPB][4];
  __shared__ int   ccnt[SPB][4];
  __shared__ float yh_l[SPB][NY];
  __shared__ float sh_theta[SPB];

  const int tid  = threadIdx.x;          // 0..511
  const int sid  = tid >> 8;             // scenario slot in block
  const int stid = tid & 255;            // obs index within scenario
  const int lane = tid & 63;
  const int wid  = (tid >> 6) & 3;       // wave within scenario
  const int t    = blockIdx.x * SPB + sid;

  const float delta = DLT[0];
  const float gamma = GMM[0];
  const float a     = fminf(delta * 0.5f, 255.0f / 256.0f);
  const float a256  = a * 256.0f;

  // ---- init: thread owns obs row stid (both sids compute same er; sid 0 writes ep) ----
  float xr[NX];
  #pragma unroll
  for (int k = 0; k < NX; ++k) xr[k] = X[stid * NX + k];

  float er[NY];
  #pragma unroll 2
  for (int j = 0; j < NY; ++j) {
    float acc = B[j];                                  // W/B wave-uniform -> scalar loads
    #pragma unroll
    for (int k = 0; k < NX; ++k) acc = fmaf(xr[k], W[j * NX + k], acc);
    float e = Y[stid * NY + j] - acc;
    er[j] = e;
    if (sid == 0) ep_t[j * CSTR + stid] = e;           // column-major, shared
    if (stid == t) { yh_l[sid][j] = acc; out[NOBS * NY + t * NY + j] = acc; }
  }
  if (sid == 0) ep_t[NY * CSTR + stid] = 1.0f;         // ones column -> c gradient
  if (stid == 0) sh_theta[sid] = FLT_MAX;              // iter 0: all candidates -> exact fallback
  __syncthreads();

  const float yhl = (lane < NY) ? yh_l[sid][lane] : 0.0f;
  float zv = (lane < NY) ? (1.0f / NY) : 0.0f;         // z one entry/lane, replicated per wave
  float cc = 0.0f;                                     // c, wave-uniform

  #pragma unroll 1
  for (int it = 0; it < NITER; ++it) {
    // ---- phase 1: forward u = ep_row . z - c (z via readlane, zero LDS) ----
    const float theta = sh_theta[sid];
    float u0 = 0.f, u1 = 0.f, u2 = 0.f, u3 = 0.f;
    #pragma unroll
    for (int k = 0; k < 48; k += 4) {
      u0 = fmaf(er[k + 0], rl_f(zv, k + 0), u0);
      u1 = fmaf(er[k + 1], rl_f(zv, k + 1), u1);
      u2 = fmaf(er[k + 2], rl_f(zv, k + 2), u2);
      u3 = fmaf(er[k + 3], rl_f(zv, k + 3), u3);
    }
    u0 = fmaf(er[48], rl_f(zv, 48), u0);
    u1 = fmaf(er[49], rl_f(zv, 49), u1);
    const float u = (u0 + u2) + (u1 + u3) - cc;
    const float r = u * u;

    // stable key: r>=0 so float bits order-isomorphic; low 32 = index (stable ties)
    const unsigned long long key =
        ((unsigned long long)(unsigned)__float_as_int(r) << 32) | (unsigned)stid;
    rrk[sid][stid] = key;

    float m = r;                                       // wave max via DPP
    DPP_MAXSTEP(m, 0x111); DPP_MAXSTEP(m, 0x112);
    DPP_MAXSTEP(m, 0x114); DPP_MAXSTEP(m, 0x118);
    DPP_MAXSTEP(m, 0x142); DPP_MAXSTEP(m, 0x143);
    if (lane == 63) wmax4[sid][wid] = m;

    const bool cond = (r < theta);
    const unsigned long long cmask = __ballot(cond);
    const int cpos = __popcll(cmask & ((1ull << lane) - 1ull));
    if (lane == 0) ccnt[sid][wid] = __popcll(cmask);
    __syncthreads();                                   // B1: rrk, wmax4, ccnt

    // ---- phase 2: max ties + candidate compaction ----
    const float mx = fmaxf(fmaxf(wmax4[sid][0], wmax4[sid][1]),
                           fmaxf(wmax4[sid][2], wmax4[sid][3]));
    const bool ismax = (r == mx);
    // BALLOT IN ALL LANES (R3 bug: ballot under lane==0 divergence -> cm=0 -> inf -> Z==0)
    const unsigned long long mmask = __ballot(ismax);
    if (lane == 0) wcnt[sid][wid] = __popcll(mmask);

    const int c0 = ccnt[sid][0], c1 = ccnt[sid][1], c2 = ccnt[sid][2], c3 = ccnt[sid][3];
    const int coff = (wid > 0 ? c0 : 0) + (wid > 1 ? c1 : 0) + (wid > 2 ? c2 : 0);
    const int C = c0 + c1 + c2 + c3;
    if (cond) ckey[sid][coff + cpos] = key;
    if (stid < 64) ckey[sid][C + stid] = ~0ull;        // sentinels cover [C, C+64) >= [C, 64)
    __syncthreads();                                   // B2: wcnt, ckey

    // ---- phase 3: exact stable rank ----
    const int  cm    = wcnt[sid][0] + wcnt[sid][1] + wcnt[sid][2] + wcnt[sid][3];
    const bool valid = ((float)C >= a256) && (C <= 64);
    int cnt;
    if (valid) {
      cnt = 300;                                       // non-candidate: rank >= C >= aN -> g=1/N
      if (cond) {
        // FIXED 64-entry scan, fully unrolled: loads issue back-to-back, one waitcnt.
        // Sentinels (~0ull) never satisfy (kk < key) -> contribute 0.
        const ulonglong2* ck2 = (const ulonglong2*)&ckey[sid][0];
        int acc_c = 0;
        #pragma unroll
        for (int j = 0; j < 32; ++j) {
          ulonglong2 kk = ck2[j];
          acc_c += (kk.x < key) ? 1 : 0;
          acc_c += (kk.y < key) ? 1 : 0;
        }
        cnt = acc_c;                                   // exact global stable rank
      }
    } else {                                           // iter 0 / drift: exact full scan
      const ulonglong2* rk2 = (const ulonglong2*)&rrk[sid][0];
      int acc_c = 0;
      #pragma unroll 8
      for (int j = 0; j < 128; ++j) {
        ulonglong2 kk = rk2[j];
        acc_c += (kk.x < key) ? 1 : 0;
        acc_c += (kk.y < key) ? 1 : 0;
      }
      cnt = acc_c;
    }
    // g_i = (1/N) clamp(rank+1-aN, 0, 1) + a*[tied max]/#ties
    const float gfac  = fminf(fmaxf((float)cnt + 1.0f - a256, 0.0f), 1.0f) * (1.0f / 256.0f);
    const float g     = gfac + (ismax ? (a / (float)cm) : 0.0f);
    const float coefv = 2.0f * u * g;
    if (cnt == THRANK) sh_theta[sid] = r;              // unique rank -> single writer

    // ---- phase 4: backward: coef via readlane, ep columns via b128 ----
    const int col = (lane < 51) ? lane : 50;
    const float4* eb = (const float4*)&ep_t[col * CSTR + wid * 64];
    float p0 = 0.f, p1 = 0.f, p2 = 0.f, p3 = 0.f;
    #pragma unroll
    for (int q = 0; q < 16; ++q) {
      float4 e4 = eb[q];
      p0 = fmaf(rl_f(coefv, 4 * q + 0), e4.x, p0);
      p1 = fmaf(rl_f(coefv, 4 * q + 1), e4.y, p1);
      p2 = fmaf(rl_f(coefv, 4 * q + 2), e4.z, p2);
      p3 = fmaf(rl_f(coefv, 4 * q + 3), e4.w, p3);
    }
    red[sid][wid * 64 + lane] = (p0 + p2) + (p1 + p3);
    __syncthreads();                                   // B3: red

    // ---- phase 5: step + counting-method simplex projection, replicated per wave ----
    const float s4 = red[sid][lane] + red[sid][64 + lane] +
                     red[sid][128 + lane] + red[sid][192 + lane];
    cc = cc + LRATE * rl_f(s4, 50);                    // gc = -sum(coef); col 50 = ones
    const float gz = s4 - gamma * yhl;
    const float v  = zv - LRATE * gz;

    int ahead = 0; float cs0 = 0.f, cs1 = 0.f;
    #pragma unroll
    for (int k = 0; k < 50; k += 2) {
      const float vk0 = rl_f(v, k);
      const float vk1 = rl_f(v, k + 1);
      const bool a0 = (vk0 > v) || (vk0 == v && (k    ) > lane);
      const bool a1 = (vk1 > v) || (vk1 == v && (k + 1) > lane);
      ahead += (a0 ? 1 : 0) + (a1 ? 1 : 0);
      cs0 += a0 ? vk0 : 0.0f;
      cs1 += a1 ? vk1 : 0.0f;
    }
    const float css = (cs0 + cs1) + v - 1.0f;
    const bool pc = (lane < NY) && (v - css / (float)(ahead + 1) > 0.0f);
    const int rho = __popcll(__ballot(pc));            // >= 1 always
    const unsigned long long bsel = __ballot((lane < NY) && (ahead == rho - 1));
    const int srcl = __ffsll(bsel) - 1;
    const float tau =
        __int_as_float(__builtin_amdgcn_readlane(__float_as_int(css), srcl)) / (float)rho;
    zv = (lane < NY) ? fmaxf(v - tau, 0.0f) : 0.0f;
  }

  if (stid < 64 && lane < NY) out[t * NY + lane] = zv; // scenario's wave 0
}

extern "C" void kernel_launch(void* const* d_in, const int* in_sizes, int n_in,
                              void* d_out, int out_size, void* d_ws, size_t ws_size,
                              hipStream_t stream) {
  (void)in_sizes; (void)n_in; (void)d_ws; (void)ws_size; (void)out_size;
  const float* X   = (const float*)d_in[0];
  const float* Y   = (const float*)d_in[1];
  const float* W   = (const float*)d_in[2];
  const float* B   = (const float*)d_in[3];
  const float* DLT = (const float*)d_in[4];
  const float* GMM = (const float*)d_in[5];
  float* out = (float*)d_out;
  hipLaunchKernelGGL(dro_kernel, dim3(NOBS / SPB), dim3(256 * SPB), 0, stream,
                     X, Y, W, B, DLT, GMM, out);
}